// Round 4
// baseline (226.990 us; speedup 1.0000x reference)
//
#include <hip/hip_runtime.h>
#include <hip/hip_bf16.h>

// Problem constants (fixed by the reference setup):
//   N = 131072 rows, D = 256 cols, num_graphs = 256, n = 512 rows/graph, K = 64
#define NROWS   131072
#define D       256
#define NGRAPH  256
#define NPG     512      // rows per graph
#define KSEL    64

// ---------------------------------------------------------------------------
// Kernel 1: one wave computes 4 row maxes. Each lane issues 4 independent
// fully-coalesced float4 loads (4 KB in flight per wave) -> HBM-saturating.
// (~20 us, at the 128 MB streaming floor — unchanged from round 3.)
// ---------------------------------------------------------------------------
__global__ __launch_bounds__(256) void row_max_kernel(const float* __restrict__ feat,
                                                      float* __restrict__ scores) {
    const int wave = (blockIdx.x * 256 + threadIdx.x) >> 6;   // global wave id
    const int lane = threadIdx.x & 63;
    const int row0 = wave * 4;                                 // 4 rows per wave

    const float4* p = reinterpret_cast<const float4*>(feat) + (size_t)row0 * 64 + lane;
    const float4 a = p[0], b = p[64], c = p[128], d = p[192];

    float m0 = fmaxf(fmaxf(a.x, a.y), fmaxf(a.z, a.w));
    float m1 = fmaxf(fmaxf(b.x, b.y), fmaxf(b.z, b.w));
    float m2 = fmaxf(fmaxf(c.x, c.y), fmaxf(c.z, c.w));
    float m3 = fmaxf(fmaxf(d.x, d.y), fmaxf(d.z, d.w));

#pragma unroll
    for (int off = 32; off > 0; off >>= 1) {
        m0 = fmaxf(m0, __shfl_xor(m0, off));
        m1 = fmaxf(m1, __shfl_xor(m1, off));
        m2 = fmaxf(m2, __shfl_xor(m2, off));
        m3 = fmaxf(m3, __shfl_xor(m3, off));
    }
    if (lane < 4) {
        const float m = (lane == 0) ? m0 : (lane == 1) ? m1 : (lane == 2) ? m2 : m3;
        scores[row0 + lane] = m;
    }
}

// ---------------------------------------------------------------------------
// Kernel 2 (NEW): one WAVE per graph. Barrier-free top-64-of-512.
// Composite key = (orderable(score) << 32) | ~local_idx, sorted DESCENDING
// by a 512-element register bitonic (8 keys/lane, e = r*64 + lane).
//   - orderable(f): sign-flip map, monotone in float order (no NaNs here)
//   - descending by key  <=>  (score desc, idx asc)  == jax.lax.top_k order
//   - j >= 64: in-lane register swap; j < 64: 64-bit __shfl_xor. Zero LDS.
// Same network as the absmax=0-verified sort_row, direction flipped.
// ---------------------------------------------------------------------------
__global__ __launch_bounds__(64) void topk_kernel(const float* __restrict__ scores,
                                                  int* __restrict__ idx_out) {
    const int g    = blockIdx.x;          // one wave = one graph
    const int lane = threadIdx.x & 63;

    const float* s = scores + (size_t)g * NPG;
    unsigned long long key[8];
#pragma unroll
    for (int r = 0; r < 8; ++r) {
        const int i = r * 64 + lane;
        const unsigned int fb = __float_as_uint(s[i]);
        const unsigned int u  = (fb & 0x80000000u) ? ~fb : (fb | 0x80000000u);
        key[r] = ((unsigned long long)u << 32) | (unsigned int)(~i);
    }

#pragma unroll
    for (int k = 2; k <= 512; k <<= 1) {
#pragma unroll
        for (int j = k >> 1; j > 0; j >>= 1) {
            if (j >= 64) {
                const int rb = j >> 6;    // 1, 2, or 4
#pragma unroll
                for (int r = 0; r < 8; ++r) {
                    if ((r & rb) == 0) {
                        const int rp = r | rb;
                        // up = ((e & k) == 0); k>=128 here -> r-bit (k>>6)
                        const bool up = (k == 512) ? true : ((r & (k >> 6)) == 0);
                        const unsigned long long lo = (key[r] < key[rp]) ? key[r] : key[rp];
                        const unsigned long long hi = (key[r] < key[rp]) ? key[rp] : key[r];
                        key[r]  = up ? hi : lo;   // descending: big at low e
                        key[rp] = up ? lo : hi;
                    }
                }
            } else {
#pragma unroll
                for (int r = 0; r < 8; ++r) {
                    const unsigned long long o = __shfl_xor(key[r], j);
                    bool up;               // up = ((e & k) == 0), e = r*64 + lane
                    if      (k <= 32)  up = ((lane & k) == 0);
                    else if (k == 64)  up = ((r & 1) == 0);
                    else if (k == 128) up = ((r & 2) == 0);
                    else if (k == 256) up = ((r & 4) == 0);
                    else               up = true;              // k == 512
                    const bool lower = ((lane & j) == 0);
                    const unsigned long long mn = (key[r] < o) ? key[r] : o;
                    const unsigned long long mx = (key[r] < o) ? o : key[r];
                    key[r] = (up == lower) ? mx : mn;          // descending
                }
            }
        }
    }

    // Positions 0..63 (descending) live in reg 0, lane = position.
    const int local = (int)(~(unsigned int)(key[0] & 0xFFFFFFFFull));
    idx_out[g * KSEL + lane] = g * NPG + local;
}

// ---------------------------------------------------------------------------
// Kernel 3: one WAVE per selected row. 256-element ascending register bitonic
// (verified absmax=0 in round 3). Zero LDS, zero barriers.
// ---------------------------------------------------------------------------
__global__ __launch_bounds__(256) void sort_row_kernel(const float* __restrict__ feat,
                                                       const int* __restrict__ idx,
                                                       float* __restrict__ out) {
    const int wv   = threadIdx.x >> 6;
    const int lane = threadIdx.x & 63;
    const int b    = blockIdx.x * 4 + wv;        // selected-row slot, 0..16383
    const int row  = idx[b];

    const float* src = feat + (size_t)row * D;
    float v[4];
#pragma unroll
    for (int r = 0; r < 4; ++r) v[r] = src[r * 64 + lane];

#pragma unroll
    for (int k = 2; k <= 256; k <<= 1) {
#pragma unroll
        for (int j = k >> 1; j > 0; j >>= 1) {
            if (j >= 64) {
                const int rb = j >> 6;           // 1 or 2
#pragma unroll
                for (int r = 0; r < 4; ++r) {
                    if ((r & rb) == 0) {
                        const int rp = r | rb;
                        const bool up = (k == 256) ? true : ((r & 2) == 0);
                        const float mn = fminf(v[r], v[rp]);
                        const float mx = fmaxf(v[r], v[rp]);
                        v[r]  = up ? mn : mx;
                        v[rp] = up ? mx : mn;
                    }
                }
            } else {
#pragma unroll
                for (int r = 0; r < 4; ++r) {
                    const float o = __shfl_xor(v[r], j);
                    bool up;
                    if      (k <= 32)  up = ((lane & k) == 0);
                    else if (k == 64)  up = ((r & 1) == 0);
                    else if (k == 128) up = ((r & 2) == 0);
                    else               up = true;              // k == 256
                    const bool lower = ((lane & j) == 0);
                    const float mn = fminf(v[r], o);
                    const float mx = fmaxf(v[r], o);
                    v[r] = (up == lower) ? mn : mx;
                }
            }
        }
    }

    float* dst = out + (size_t)b * D;
#pragma unroll
    for (int r = 0; r < 4; ++r) dst[r * 64 + lane] = v[r];
}

// ---------------------------------------------------------------------------
extern "C" void kernel_launch(void* const* d_in, const int* in_sizes, int n_in,
                              void* d_out, int out_size, void* d_ws, size_t ws_size,
                              hipStream_t stream) {
    const float* feat = (const float*)d_in[0];
    float* out = (float*)d_out;

    // Workspace layout: [ scores: NROWS floats | topk idx: NGRAPH*KSEL ints ]
    float* scores = (float*)d_ws;
    int*   idx    = (int*)((char*)d_ws + (size_t)NROWS * sizeof(float));

    // Stage 1: row maxes. 4 rows/wave -> 32768 waves -> 8192 blocks of 256.
    row_max_kernel<<<NROWS / 16, 256, 0, stream>>>(feat, scores);

    // Stage 2: per-graph top-64, one wave per graph, barrier-free.
    topk_kernel<<<NGRAPH, 64, 0, stream>>>(scores, idx);

    // Stage 3: register-bitonic sort of the 16384 winning rows, 1 wave/row.
    sort_row_kernel<<<NGRAPH * KSEL / 4, 256, 0, stream>>>(feat, idx, out);
}